// Round 1
// baseline (2020.709 us; speedup 1.0000x reference)
//
#include <hip/hip_runtime.h>
#include <math.h>

#define DIM 192
#define HEADS 6
#define HD 32
#define WS 7
#define NN 49
#define NWIN 4096
#define THREADS 256
#define QKV_ROW (3*DIM)

__device__ __forceinline__ float gelu_tanh(float x) {
    const float k0 = 0.7978845608028654f; // sqrt(2/pi)
    const float k1 = 0.044715f;
    float t = tanhf(k0 * (x + k1 * x * x * x));
    return 0.5f * x * (1.0f + t);
}

__device__ __forceinline__ float sigmoidf(float x) {
    return 1.0f / (1.0f + __expf(-x));
}

// ---------------- bias kernel: (6,49,49) into d_ws ----------------
__global__ __launch_bounds__(128) void bias_kernel(
    const float* __restrict__ pos_w, const float* __restrict__ pos_scale,
    const float* __restrict__ meta_w1, const float* __restrict__ meta_b1,
    const float* __restrict__ meta_w2, const float* __restrict__ meta_b2,
    float* __restrict__ bias_out)
{
    const int p = blockIdx.x;          // 0..2400  (n*49+m)
    const int n = p / NN, m = p % NN;
    const int i = threadIdx.x;         // 0..127
    __shared__ float hbuf[128];
    const float step = 2.0f / 6.0f;    // linspace(-1,1,7) spacing
    const float dx = (float)((n % WS) - (m % WS)) * step;
    const float dy = (float)((n / WS) - (m / WS)) * step;
    const float ps = pos_scale[0];
    float a = meta_b1[i];
    for (int d = 0; d < DIM; ++d) {
        float rel = ps * (pos_w[2*d] * dx + pos_w[2*d+1] * dy); // pos_b cancels
        a += rel * meta_w1[d*128 + i];
    }
    hbuf[i] = gelu_tanh(a);
    __syncthreads();
    if (i < HEADS) {
        float b = meta_b2[i];
        for (int j = 0; j < 128; ++j) b += hbuf[j] * meta_w2[j*HEADS + i];
        bias_out[i*(NN*NN) + p] = b;   // bias[h][n][m]
    }
}

// ---------------- PDSCA gate (in-place on LDS x, flat j = n*32+d = c*49+s) ----
__device__ __forceinline__ void apply_gate(
    float* xs,
    const float* __restrict__ ca_w1, const float* __restrict__ ca_b1,
    const float* __restrict__ ca_w2, const float* __restrict__ ca_b2,
    const float* __restrict__ sa_w, const float* __restrict__ sa_b,
    float* cmean, float* hb, float* caout, float* smean, float* smax, float* sabuf,
    int t)
{
    // phase 1: channel means (t<32) || spatial mean/max over channels (t in [64,113))
    if (t < HD) {
        float s = 0.0f;
        for (int j = 0; j < NN; ++j) s += xs[t*NN + j];   // stride-49 across lanes: conflict-free
        cmean[t] = s * (1.0f/NN);
    } else if (t >= 64 && t < 64 + NN) {
        int sp = t - 64;
        float sm = 0.0f, mxv = -1e30f;
        for (int c = 0; c < HD; ++c) {
            float vx = xs[c*NN + sp];
            sm += vx;
            mxv = fmaxf(mxv, vx);
        }
        smean[sp] = sm * (1.0f/HD);
        smax[sp] = mxv;
    }
    __syncthreads();
    // phase 2: MLP hidden (t<8) || 7x7 SAME conv (t in [64,113))
    if (t < 8) {
        float a = ca_b1[t];
        #pragma unroll
        for (int c = 0; c < HD; ++c) a += ca_w1[t*HD + c] * cmean[c];
        hb[t] = gelu_tanh(a);
    } else if (t >= 64 && t < 64 + NN) {
        int sp = t - 64;
        int y = sp / WS, x = sp - y*WS;
        float a = sa_b[0];
        for (int ky = 0; ky < WS; ++ky) {
            int iy = y + ky - 3;
            if (iy < 0 || iy >= WS) continue;
            for (int kx = 0; kx < WS; ++kx) {
                int ix = x + kx - 3;
                if (ix < 0 || ix >= WS) continue;
                int s2 = iy*WS + ix;
                a += sa_w[ky*WS+kx] * smean[s2] + sa_w[NN + ky*WS+kx] * smax[s2];
            }
        }
        sabuf[sp] = a;
    }
    __syncthreads();
    // phase 3: channel-attention output (t<32)
    if (t < HD) {
        float a = ca_b2[t];
        #pragma unroll
        for (int i = 0; i < 8; ++i) a += ca_w2[t*8 + i] * hb[i];
        caout[t] = a;
    }
    __syncthreads();
    // phase 4: gate
    for (int j = t; j < NN*HD; j += THREADS) {
        int c = j / NN, sp = j - c*NN;
        xs[j] *= sigmoidf(caout[c] + sabuf[sp]);
    }
    __syncthreads();
}

// ---------------- main fused kernel: one block per window ----------------
__global__ __launch_bounds__(THREADS, 3) void win_attn_kernel(
    const float* __restrict__ qkv,
    const float* __restrict__ log_temp,
    const float* __restrict__ q_ca_w1, const float* __restrict__ q_ca_b1,
    const float* __restrict__ q_ca_w2, const float* __restrict__ q_ca_b2,
    const float* __restrict__ q_sa_w, const float* __restrict__ q_sa_b,
    const float* __restrict__ k_ca_w1, const float* __restrict__ k_ca_b1,
    const float* __restrict__ k_ca_w2, const float* __restrict__ k_ca_b2,
    const float* __restrict__ k_sa_w, const float* __restrict__ k_sa_b,
    const float* __restrict__ proj_w,
    const float* __restrict__ bias,
    float* __restrict__ out)
{
    __shared__ float q_s[NN*HD];      // 1568; holds O after PV
    __shared__ float k_s[NN*HD];
    __shared__ float v_s[NN*HD];
    __shared__ float uni[6400];       // attn(2401)+k_t(@2432,1568)  OR  pw[192][33]
    __shared__ float cmean[HD], hb[8], caout[HD], smean[NN], smax[NN], sabuf[NN];

    float* attn_s = uni;
    float* k_t    = uni + 2432;       // [32][49]
    float* pw_s   = uni;              // [192][33] head slice of proj_w

    const int b = blockIdx.x;
    const int t = threadIdx.x;
    const int tn = t >> 5;            // 0..7   (n-group)
    const int tf = t & 31;            // 0..31  (f-lane)
    const float temp = __expf(log_temp[0]);
    const float* qkv_b = qkv + (size_t)b * (NN*QKV_ROW);

    float acc[7][6];
    #pragma unroll
    for (int i = 0; i < 7; ++i)
        #pragma unroll
        for (int j = 0; j < 6; ++j) acc[i][j] = 0.0f;

    #pragma unroll 1
    for (int h = 0; h < HEADS; ++h) {
        // stage q,k,v for head h (float4, rows are 128B-aligned)
        for (int e4 = t; e4 < NN*HD/4; e4 += THREADS) {
            int n = e4 >> 3, d4 = e4 & 7;
            const float4* row = (const float4*)(qkv_b + n*QKV_ROW + h*HD) + d4;
            ((float4*)q_s)[e4] = row[0];
            ((float4*)k_s)[e4] = row[DIM/4];
            ((float4*)v_s)[e4] = row[2*(DIM/4)];
        }
        __syncthreads();

        apply_gate(q_s, q_ca_w1, q_ca_b1, q_ca_w2, q_ca_b2, q_sa_w, q_sa_b,
                   cmean, hb, caout, smean, smax, sabuf, t);
        apply_gate(k_s, k_ca_w1, k_ca_b1, k_ca_w2, k_ca_b2, k_sa_w, k_sa_b,
                   cmean, hb, caout, smean, smax, sabuf, t);

        // transpose K -> k_t[d][m] (avoids 32-way bank conflict in S)
        for (int e = t; e < NN*HD; e += THREADS)
            k_t[(e & 31)*NN + (e >> 5)] = k_s[e];
        __syncthreads();

        // S = temp * q k^T + bias[h]
        const float* bias_h = bias + h*(NN*NN);
        for (int idx = t; idx < NN*NN; idx += THREADS) {
            int n = idx / NN, m = idx - n*NN;
            const float* qrow = q_s + n*HD;
            float s = 0.0f;
            #pragma unroll
            for (int d = 0; d < HD; ++d) s += qrow[d] * k_t[d*NN + m];
            attn_s[idx] = s * temp + bias_h[idx];
        }
        __syncthreads();

        // softmax rows: 4 lanes per row
        if (t < 4*NN) {
            int n = t >> 2, sub = t & 3;
            float* prow = attn_s + n*NN;
            float mx = -1e30f;
            for (int m = sub; m < NN; m += 4) mx = fmaxf(mx, prow[m]);
            mx = fmaxf(mx, __shfl_xor(mx, 1, 64));
            mx = fmaxf(mx, __shfl_xor(mx, 2, 64));
            float sum = 0.0f;
            for (int m = sub; m < NN; m += 4) {
                float e = __expf(prow[m] - mx);
                prow[m] = e;
                sum += e;
            }
            sum += __shfl_xor(sum, 1, 64);
            sum += __shfl_xor(sum, 2, 64);
            float inv = 1.0f / sum;
            for (int m = sub; m < NN; m += 4) prow[m] *= inv;
        }
        __syncthreads();

        // O = P V  -> overwrite q_s
        for (int idx = t; idx < NN*HD; idx += THREADS) {
            int n = idx >> 5, d = idx & 31;
            const float* prow = attn_s + n*NN;
            float o = 0.0f;
            #pragma unroll 7
            for (int m = 0; m < NN; ++m) o += prow[m] * v_s[m*HD + d];
            q_s[idx] = o;
        }
        __syncthreads();

        // stage proj_w head slice -> pw_s[f][33] (coalesced read, padded store)
        for (int e = t; e < DIM*8; e += THREADS) {
            int f = e >> 3, d4 = e & 7;
            float4 w = *((const float4*)(proj_w + f*DIM + h*HD) + d4);
            float* dst = pw_s + f*33 + d4*4;
            dst[0] = w.x; dst[1] = w.y; dst[2] = w.z; dst[3] = w.w;
        }
        __syncthreads();

        // projection partial: acc[in][jf] += O[n][d] * proj_w[f][h*32+d]
        #pragma unroll 8
        for (int dd = 0; dd < HD; ++dd) {
            float ov[7];
            #pragma unroll
            for (int in_ = 0; in_ < 7; ++in_) {
                int n = tn + (in_ << 3);
                n = n < NN ? n : NN-1;           // clamp; guarded at store
                ov[in_] = q_s[n*HD + dd];
            }
            #pragma unroll
            for (int jf = 0; jf < 6; ++jf) {
                float w = pw_s[(tf + (jf << 5))*33 + dd];
                #pragma unroll
                for (int in_ = 0; in_ < 7; ++in_)
                    acc[in_][jf] += ov[in_] * w;
            }
        }
        __syncthreads();
    }

    float* out_b = out + (size_t)b * (NN*DIM);
    #pragma unroll
    for (int in_ = 0; in_ < 7; ++in_) {
        int n = tn + (in_ << 3);
        if (n < NN) {
            #pragma unroll
            for (int jf = 0; jf < 6; ++jf)
                out_b[n*DIM + tf + (jf << 5)] = acc[in_][jf];
        }
    }
}

extern "C" void kernel_launch(void* const* d_in, const int* in_sizes, int n_in,
                              void* d_out, int out_size, void* d_ws, size_t ws_size,
                              hipStream_t stream)
{
    (void)in_sizes; (void)n_in; (void)out_size; (void)ws_size;
    const float* qkv      = (const float*)d_in[0];
    const float* log_temp = (const float*)d_in[1];
    const float* pos_w    = (const float*)d_in[2];
    /* d_in[3] = pos_b cancels in pairwise diff */
    const float* pos_scale= (const float*)d_in[4];
    const float* meta_w1  = (const float*)d_in[5];
    const float* meta_b1  = (const float*)d_in[6];
    const float* meta_w2  = (const float*)d_in[7];
    const float* meta_b2  = (const float*)d_in[8];
    const float* q_ca_w1  = (const float*)d_in[9];
    const float* q_ca_b1  = (const float*)d_in[10];
    const float* q_ca_w2  = (const float*)d_in[11];
    const float* q_ca_b2  = (const float*)d_in[12];
    const float* q_sa_w   = (const float*)d_in[13];
    const float* q_sa_b   = (const float*)d_in[14];
    const float* k_ca_w1  = (const float*)d_in[15];
    const float* k_ca_b1  = (const float*)d_in[16];
    const float* k_ca_w2  = (const float*)d_in[17];
    const float* k_ca_b2  = (const float*)d_in[18];
    const float* k_sa_w   = (const float*)d_in[19];
    const float* k_sa_b   = (const float*)d_in[20];
    const float* proj_w   = (const float*)d_in[21];
    float* out = (float*)d_out;
    float* bias_ws = (float*)d_ws;   // 6*49*49 floats

    hipLaunchKernelGGL(bias_kernel, dim3(NN*NN), dim3(128), 0, stream,
                       pos_w, pos_scale, meta_w1, meta_b1, meta_w2, meta_b2, bias_ws);
    hipLaunchKernelGGL(win_attn_kernel, dim3(NWIN), dim3(THREADS), 0, stream,
                       qkv, log_temp,
                       q_ca_w1, q_ca_b1, q_ca_w2, q_ca_b2, q_sa_w, q_sa_b,
                       k_ca_w1, k_ca_b1, k_ca_w2, k_ca_b2, k_sa_w, k_sa_b,
                       proj_w, bias_ws, out);
}

// Round 2
// 568.420 us; speedup vs baseline: 3.5550x; 3.5550x over previous
//
#include <hip/hip_runtime.h>
#include <math.h>

#define DIM 192
#define HEADS 6
#define HD 32
#define WS 7
#define NN 49
#define NWIN 4096
#define QKV_ROW (3*DIM)

typedef __attribute__((ext_vector_type(8))) short bf16x8_t;
typedef __attribute__((ext_vector_type(4))) float f32x4_t;

#define MFMA16(a,b,c) __builtin_amdgcn_mfma_f32_16x16x32_bf16((a),(b),(c),0,0,0)

__device__ __forceinline__ float gelu_tanh(float x) {
    const float k0 = 0.7978845608028654f; // sqrt(2/pi)
    const float k1 = 0.044715f;
    float t = tanhf(k0 * (x + k1 * x * x * x));
    return 0.5f * x * (1.0f + t);
}

__device__ __forceinline__ unsigned short f2bf(float x) {
    unsigned int u = __float_as_uint(x);
    unsigned int r = (u + 0x7FFFu + ((u >> 16) & 1u)) >> 16;  // RNE
    return (unsigned short)r;
}
__device__ __forceinline__ float bf2f(unsigned short u) {
    return __uint_as_float(((unsigned int)u) << 16);
}

// ---------------- bias kernel: (6,49,49) into d_ws (unchanged, verified) ----
__global__ __launch_bounds__(128) void bias_kernel(
    const float* __restrict__ pos_w, const float* __restrict__ pos_scale,
    const float* __restrict__ meta_w1, const float* __restrict__ meta_b1,
    const float* __restrict__ meta_w2, const float* __restrict__ meta_b2,
    float* __restrict__ bias_out)
{
    const int p = blockIdx.x;          // n*49+m
    const int n = p / NN, m = p % NN;
    const int i = threadIdx.x;         // 0..127
    __shared__ float hbuf[128];
    const float step = 2.0f / 6.0f;
    const float dx = (float)((n % WS) - (m % WS)) * step;
    const float dy = (float)((n / WS) - (m / WS)) * step;
    const float ps = pos_scale[0];
    float a = meta_b1[i];
    for (int d = 0; d < DIM; ++d) {
        float rel = ps * (pos_w[2*d] * dx + pos_w[2*d+1] * dy); // pos_b cancels
        a += rel * meta_w1[d*128 + i];
    }
    hbuf[i] = gelu_tanh(a);
    __syncthreads();
    if (i < HEADS) {
        float b = meta_b2[i];
        for (int j = 0; j < 128; ++j) b += hbuf[j] * meta_w2[j*HEADS + i];
        bias_out[i*(NN*NN) + p] = b;   // bias[h][n][m]
    }
}

// gate scratch layout (floats)
#define CM 0
#define HB 32
#define CA 40
#define SM 72
#define SX 121
#define SB 170
#define GSZ 219

// LDS row strides (in bf16 elems)
#define RSQ 40   // q_s/k_s/o_s/w_s: 80B
#define RSV 72   // v_t/p_s: 144B

__global__ __launch_bounds__(256, 3) void win_attn_mfma(
    const float* __restrict__ qkv,
    const float* __restrict__ log_temp,
    const float* __restrict__ q_ca_w1, const float* __restrict__ q_ca_b1,
    const float* __restrict__ q_ca_w2, const float* __restrict__ q_ca_b2,
    const float* __restrict__ q_sa_w, const float* __restrict__ q_sa_b,
    const float* __restrict__ k_ca_w1, const float* __restrict__ k_ca_b1,
    const float* __restrict__ k_ca_w2, const float* __restrict__ k_ca_b2,
    const float* __restrict__ k_sa_w, const float* __restrict__ k_sa_b,
    const float* __restrict__ proj_w,
    const float* __restrict__ bias,
    float* __restrict__ out)
{
    __shared__ unsigned short q_s[64*RSQ];   // gated Q, later O (bf16)
    __shared__ unsigned short k_s[64*RSQ];   // gated K
    __shared__ unsigned short v_t[32*RSV];   // V transposed [d][m]
    __shared__ unsigned short p_s[64*RSV];   // P [n][m]
    __shared__ unsigned short w_s[192*RSQ];  // proj_w head slice [f][d]
    __shared__ float gsc[2*GSZ];

    const int t = threadIdx.x;
    const int b = blockIdx.x;
    const int l = t & 63;
    const int w = t >> 6;          // wave / row-strip
    const int lrow = l & 15;
    const int lk = l >> 4;
    const float temp = __expf(log_temp[0]);
    const float* qkv_b = qkv + (size_t)b * (NN*QKV_ROW);

    // gate partition: waves 0,1 -> q; waves 2,3 -> k
    const int kh = t >> 7;
    const int tt = t & 127;
    unsigned short* xs = kh ? k_s : q_s;
    const float* ca_w1 = kh ? k_ca_w1 : q_ca_w1;
    const float* ca_b1 = kh ? k_ca_b1 : q_ca_b1;
    const float* ca_w2 = kh ? k_ca_w2 : q_ca_w2;
    const float* ca_b2 = kh ? k_ca_b2 : q_ca_b2;
    const float* sa_w  = kh ? k_sa_w  : q_sa_w;
    const float* sa_b  = kh ? k_sa_b  : q_sa_b;
    float* sc = gsc + kh*GSZ;

    f32x4_t pacc[12];
    #pragma unroll
    for (int j = 0; j < 12; ++j) pacc[j] = (f32x4_t){0.f,0.f,0.f,0.f};

    // zero pad regions once: q/k rows 49..63, v_t cols 49..71
    for (int i = t; i < 15*RSQ; i += 256) { q_s[49*RSQ + i] = 0; k_s[49*RSQ + i] = 0; }
    for (int i = t; i < 32*23; i += 256) { int d = i/23, m = 49 + (i - d*23); v_t[d*RSV + m] = 0; }

    #pragma unroll 1
    for (int h = 0; h < HEADS; ++h) {
        // ---- stage q,k,v head slice (fp32 -> bf16) ----
        for (int e = t; e < NN*8; e += 256) {
            int n = e >> 3, c = e & 7;
            const float* base = qkv_b + n*QKV_ROW + h*HD + c*4;
            float4 fq = *(const float4*)(base);
            float4 fk = *(const float4*)(base + DIM);
            float4 fv = *(const float4*)(base + 2*DIM);
            ushort4 uq = { f2bf(fq.x), f2bf(fq.y), f2bf(fq.z), f2bf(fq.w) };
            ushort4 uk = { f2bf(fk.x), f2bf(fk.y), f2bf(fk.z), f2bf(fk.w) };
            *(ushort4*)&q_s[n*RSQ + c*4] = uq;
            *(ushort4*)&k_s[n*RSQ + c*4] = uk;
            int d0 = c*4;
            v_t[(d0+0)*RSV + n] = f2bf(fv.x);
            v_t[(d0+1)*RSV + n] = f2bf(fv.y);
            v_t[(d0+2)*RSV + n] = f2bf(fv.z);
            v_t[(d0+3)*RSV + n] = f2bf(fv.w);
        }
        __syncthreads();

        // ---- PDSCA gates: q on tt-half 0, k on half 1 (flat j=n*32+d; c=j/49, s=j%49)
        if (tt < HD) {                       // channel means
            float s = 0.f;
            int j = tt*NN;
            for (int sp = 0; sp < NN; ++sp, ++j)
                s += bf2f(xs[(j>>5)*RSQ + (j&31)]);
            sc[CM + tt] = s * (1.f/NN);
        } else if (tt >= 64 && tt < 64+NN) { // spatial mean/max
            int sp = tt - 64;
            float sm = 0.f, mx = -1e30f;
            for (int c = 0; c < HD; ++c) {
                int j = c*NN + sp;
                float v = bf2f(xs[(j>>5)*RSQ + (j&31)]);
                sm += v; mx = fmaxf(mx, v);
            }
            sc[SM+sp] = sm * (1.f/HD); sc[SX+sp] = mx;
        }
        __syncthreads();
        if (tt < 8) {                        // MLP hidden
            float a = ca_b1[tt];
            #pragma unroll
            for (int c = 0; c < HD; ++c) a += ca_w1[tt*HD + c] * sc[CM+c];
            sc[HB+tt] = gelu_tanh(a);
        } else if (tt >= 64 && tt < 64+NN) { // 7x7 SAME conv
            int sp = tt - 64;
            int y = sp / WS, x = sp - y*WS;
            float a = sa_b[0];
            for (int ky = 0; ky < WS; ++ky) {
                int iy = y + ky - 3;
                if (iy < 0 || iy >= WS) continue;
                for (int kx = 0; kx < WS; ++kx) {
                    int ix = x + kx - 3;
                    if (ix < 0 || ix >= WS) continue;
                    int s2 = iy*WS + ix;
                    a += sa_w[ky*WS+kx] * sc[SM+s2] + sa_w[NN + ky*WS+kx] * sc[SX+s2];
                }
            }
            sc[SB+sp] = a;
        }
        __syncthreads();
        if (tt < HD) {                       // channel out
            float a = ca_b2[tt];
            #pragma unroll
            for (int i = 0; i < 8; ++i) a += ca_w2[tt*8 + i] * sc[HB+i];
            sc[CA+tt] = a;
        }
        __syncthreads();
        for (int j = tt; j < NN*HD; j += 128) {  // sigmoid gate multiply
            int n = j >> 5, d = j & 31;
            int c = j / NN, sp = j - c*NN;
            int idx = n*RSQ + d;
            float v = bf2f(xs[idx]);
            float g = 1.f / (1.f + __expf(-(sc[CA+c] + sc[SB+sp])));
            xs[idx] = f2bf(v * g);
        }
        __syncthreads();

        // ---- S = Q K^T (4 MFMAs per wave, 16-row strip w) ----
        bf16x8_t aq = *(const bf16x8_t*)&q_s[(w*16 + lrow)*RSQ + lk*8];
        f32x4_t sac[4];
        #pragma unroll
        for (int j = 0; j < 4; ++j) {
            bf16x8_t bk = *(const bf16x8_t*)&k_s[(j*16 + lrow)*RSQ + lk*8];
            f32x4_t z = (f32x4_t){0.f,0.f,0.f,0.f};
            sac[j] = MFMA16(aq, bk, z);
        }

        // stage proj_w head slice while S cooks (read at proj after barrier)
        for (int e = t; e < DIM*8; e += 256) {
            int f = e >> 3, c = e & 7;
            float4 wv = *(const float4*)(proj_w + f*DIM + h*HD + c*4);
            ushort4 uw = { f2bf(wv.x), f2bf(wv.y), f2bf(wv.z), f2bf(wv.w) };
            *(ushort4*)&w_s[f*RSQ + c*4] = uw;
        }

        // ---- bias + temp + softmax (rows lk*4+r, cols j*16+lrow) ----
        const float* bias_h = bias + h*(NN*NN);
        #pragma unroll
        for (int r = 0; r < 4; ++r) {
            int row = w*16 + lk*4 + r;
            float vals[4];
            #pragma unroll
            for (int j = 0; j < 4; ++j) {
                int col = j*16 + lrow;
                float sv = -1e30f;
                if (col < NN) {
                    sv = sac[j][r] * temp;
                    if (row < NN) sv += bias_h[row*NN + col];
                }
                vals[j] = sv;
            }
            float mx = fmaxf(fmaxf(vals[0], vals[1]), fmaxf(vals[2], vals[3]));
            mx = fmaxf(mx, __shfl_xor(mx, 1));
            mx = fmaxf(mx, __shfl_xor(mx, 2));
            mx = fmaxf(mx, __shfl_xor(mx, 4));
            mx = fmaxf(mx, __shfl_xor(mx, 8));
            float sum = 0.f;
            #pragma unroll
            for (int j = 0; j < 4; ++j) { float e = __expf(vals[j] - mx); vals[j] = e; sum += e; }
            sum += __shfl_xor(sum, 1);
            sum += __shfl_xor(sum, 2);
            sum += __shfl_xor(sum, 4);
            sum += __shfl_xor(sum, 8);
            float inv = 1.f / sum;
            #pragma unroll
            for (int j = 0; j < 4; ++j)
                p_s[row*RSV + j*16 + lrow] = f2bf(vals[j] * inv);
        }
        __syncthreads();   // covers w_s staging (P/O paths are same-wave)

        // ---- O = P V (K=64 over m; cols 49..63 of P are exactly 0) ----
        f32x4_t oac[2];
        oac[0] = (f32x4_t){0.f,0.f,0.f,0.f};
        oac[1] = (f32x4_t){0.f,0.f,0.f,0.f};
        #pragma unroll
        for (int ks = 0; ks < 2; ++ks) {
            bf16x8_t ap = *(const bf16x8_t*)&p_s[(w*16 + lrow)*RSV + ks*32 + lk*8];
            #pragma unroll
            for (int nt = 0; nt < 2; ++nt) {
                bf16x8_t bv = *(const bf16x8_t*)&v_t[(nt*16 + lrow)*RSV + ks*32 + lk*8];
                oac[nt] = MFMA16(ap, bv, oac[nt]);
            }
        }
        // O -> o_s (reuse q_s; strip-local, same wave)
        #pragma unroll
        for (int nt = 0; nt < 2; ++nt)
            #pragma unroll
            for (int r = 0; r < 4; ++r)
                q_s[(w*16 + lk*4 + r)*RSQ + nt*16 + lrow] = f2bf(oac[nt][r]);

        // ---- projection partial: pacc[j] += O * W_h (12 MFMAs) ----
        bf16x8_t ao = *(const bf16x8_t*)&q_s[(w*16 + lrow)*RSQ + lk*8];
        #pragma unroll
        for (int j = 0; j < 12; ++j) {
            bf16x8_t bw = *(const bf16x8_t*)&w_s[(j*16 + lrow)*RSQ + lk*8];
            pacc[j] = MFMA16(ao, bw, pacc[j]);
        }
        __syncthreads();   // protect q_s/k_s/v_t/w_s before next head's stage
    }

    // ---- store: row = strip + lk*4 + r, col = j*16 + lrow ----
    float* out_b = out + (size_t)b * (NN*DIM);
    #pragma unroll
    for (int j = 0; j < 12; ++j) {
        #pragma unroll
        for (int r = 0; r < 4; ++r) {
            int row = w*16 + lk*4 + r;
            if (row < NN)
                out_b[row*DIM + j*16 + lrow] = pacc[j][r];
        }
    }
}

extern "C" void kernel_launch(void* const* d_in, const int* in_sizes, int n_in,
                              void* d_out, int out_size, void* d_ws, size_t ws_size,
                              hipStream_t stream)
{
    (void)in_sizes; (void)n_in; (void)out_size; (void)ws_size;
    const float* qkv      = (const float*)d_in[0];
    const float* log_temp = (const float*)d_in[1];
    const float* pos_w    = (const float*)d_in[2];
    /* d_in[3] = pos_b cancels in pairwise diff */
    const float* pos_scale= (const float*)d_in[4];
    const float* meta_w1  = (const float*)d_in[5];
    const float* meta_b1  = (const float*)d_in[6];
    const float* meta_w2  = (const float*)d_in[7];
    const float* meta_b2  = (const float*)d_in[8];
    const float* q_ca_w1  = (const float*)d_in[9];
    const float* q_ca_b1  = (const float*)d_in[10];
    const float* q_ca_w2  = (const float*)d_in[11];
    const float* q_ca_b2  = (const float*)d_in[12];
    const float* q_sa_w   = (const float*)d_in[13];
    const float* q_sa_b   = (const float*)d_in[14];
    const float* k_ca_w1  = (const float*)d_in[15];
    const float* k_ca_b1  = (const float*)d_in[16];
    const float* k_ca_w2  = (const float*)d_in[17];
    const float* k_ca_b2  = (const float*)d_in[18];
    const float* k_sa_w   = (const float*)d_in[19];
    const float* k_sa_b   = (const float*)d_in[20];
    const float* proj_w   = (const float*)d_in[21];
    float* out = (float*)d_out;
    float* bias_ws = (float*)d_ws;   // 6*49*49 floats

    hipLaunchKernelGGL(bias_kernel, dim3(NN*NN), dim3(128), 0, stream,
                       pos_w, pos_scale, meta_w1, meta_b1, meta_w2, meta_b2, bias_ws);
    hipLaunchKernelGGL(win_attn_mfma, dim3(NWIN), dim3(256), 0, stream,
                       qkv, log_temp,
                       q_ca_w1, q_ca_b1, q_ca_w2, q_ca_b2, q_sa_w, q_sa_b,
                       k_ca_w1, k_ca_b1, k_ca_w2, k_ca_b2, k_sa_w, k_sa_b,
                       proj_w, bias_ws, out);
}